// Round 1
// baseline (23.967 us; speedup 1.0000x reference)
//
#include <hip/hip_runtime.h>

// SeparableWeightedConv: depthwise 1D conv (K=9, pad=4) with per-(b,l,k)
// distance weights dw = max(1 - |coords_tap - coords_center| / sigma, 0).
// Memory-bound: 32MB x read + 32MB out write. dw computed per-thread into
// registers once, reused across CH channels.

#define BB 8
#define CC 128
#define NN 8192
#define KK 9

constexpr int CH      = 8;            // channels per block
constexpr int CGROUPS = CC / CH;      // 16
constexpr int LTILE   = 1024;         // l positions per block (256 thr x 4)
constexpr int LTILES  = NN / LTILE;   // 8
constexpr int THREADS = 256;

__global__ __launch_bounds__(THREADS)
void sepwconv_kernel(const float* __restrict__ x,
                     const float* __restrict__ coords,
                     const float* __restrict__ sigma,
                     const float* __restrict__ weight,
                     float* __restrict__ out)
{
    const int bid = blockIdx.x;
    const int cg  = bid % CGROUPS;
    const int lt  = (bid / CGROUPS) % LTILES;
    const int b   = bid / (CGROUPS * LTILES);
    const int t   = threadIdx.x;
    const int l0  = lt * LTILE + t * 4;   // this thread's 4 output positions

    const float inv_sigma = 1.0f / sigma[0];

    const float* cx = coords + (size_t)(b * 3 + 0) * NN;
    const float* cy = coords + (size_t)(b * 3 + 1) * NN;
    const float* cz = coords + (size_t)(b * 3 + 2) * NN;

    // taps for outputs l0..l0+3 span positions l0-4 .. l0+7 (12 values)
    const bool interior = (l0 >= 4) && (l0 + 8 <= NN);

    float cxv[12], cyv[12], czv[12];
    if (interior) {
        float4 a, bq, cq;
        a = *(const float4*)(cx + l0 - 4); bq = *(const float4*)(cx + l0); cq = *(const float4*)(cx + l0 + 4);
        cxv[0]=a.x;cxv[1]=a.y;cxv[2]=a.z;cxv[3]=a.w; cxv[4]=bq.x;cxv[5]=bq.y;cxv[6]=bq.z;cxv[7]=bq.w; cxv[8]=cq.x;cxv[9]=cq.y;cxv[10]=cq.z;cxv[11]=cq.w;
        a = *(const float4*)(cy + l0 - 4); bq = *(const float4*)(cy + l0); cq = *(const float4*)(cy + l0 + 4);
        cyv[0]=a.x;cyv[1]=a.y;cyv[2]=a.z;cyv[3]=a.w; cyv[4]=bq.x;cyv[5]=bq.y;cyv[6]=bq.z;cyv[7]=bq.w; cyv[8]=cq.x;cyv[9]=cq.y;cyv[10]=cq.z;cyv[11]=cq.w;
        a = *(const float4*)(cz + l0 - 4); bq = *(const float4*)(cz + l0); cq = *(const float4*)(cz + l0 + 4);
        czv[0]=a.x;czv[1]=a.y;czv[2]=a.z;czv[3]=a.w; czv[4]=bq.x;czv[5]=bq.y;czv[6]=bq.z;czv[7]=bq.w; czv[8]=cq.x;czv[9]=cq.y;czv[10]=cq.z;czv[11]=cq.w;
    } else {
        #pragma unroll
        for (int j = 0; j < 12; ++j) {
            int p = l0 - 4 + j;
            p = p < 0 ? 0 : (p >= NN ? NN - 1 : p);  // clamp: OOB taps hit x==0 anyway
            cxv[j] = cx[p]; cyv[j] = cy[p]; czv[j] = cz[p];
        }
    }

    // dw[jl][k] for this thread's 4 l positions; center tap is k=4 -> j=jl+4
    float dw[4][KK];
    #pragma unroll
    for (int jl = 0; jl < 4; ++jl) {
        const float ccx = cxv[jl + 4], ccy = cyv[jl + 4], ccz = czv[jl + 4];
        #pragma unroll
        for (int k = 0; k < KK; ++k) {
            const float dx = cxv[jl + k] - ccx;
            const float dy = cyv[jl + k] - ccy;
            const float dz = czv[jl + k] - ccz;
            const float sq = fmaf(dx, dx, fmaf(dy, dy, dz * dz));
            const float dist = sqrtf(sq);              // sq==0 -> 0, matches ref
            dw[jl][k] = fmaxf(1.0f - dist * inv_sigma, 0.0f);
        }
    }

    // channel loop: reuse dw registers across CH channels
    #pragma unroll 1
    for (int i = 0; i < CH; ++i) {
        const int c = cg * CH + i;
        const float* wr = weight + c * KK;   // uniform address -> s_load
        float w[KK];
        #pragma unroll
        for (int k = 0; k < KK; ++k) w[k] = wr[k];

        const float* xr = x + ((size_t)b * CC + c) * NN;
        float xv[12];
        if (interior) {
            float4 a  = *(const float4*)(xr + l0 - 4);
            float4 bq = *(const float4*)(xr + l0);
            float4 cq = *(const float4*)(xr + l0 + 4);
            xv[0]=a.x;xv[1]=a.y;xv[2]=a.z;xv[3]=a.w; xv[4]=bq.x;xv[5]=bq.y;xv[6]=bq.z;xv[7]=bq.w; xv[8]=cq.x;xv[9]=cq.y;xv[10]=cq.z;xv[11]=cq.w;
        } else {
            #pragma unroll
            for (int j = 0; j < 12; ++j) {
                int p = l0 - 4 + j;
                xv[j] = (p >= 0 && p < NN) ? xr[p] : 0.0f;  // zero-pad
            }
        }

        float acc[4] = {0.f, 0.f, 0.f, 0.f};
        #pragma unroll
        for (int jl = 0; jl < 4; ++jl) {
            #pragma unroll
            for (int k = 0; k < KK; ++k) {
                acc[jl] = fmaf(xv[jl + k] * dw[jl][k], w[k], acc[jl]);
            }
        }

        float4 o; o.x = acc[0]; o.y = acc[1]; o.z = acc[2]; o.w = acc[3];
        *(float4*)(out + ((size_t)b * CC + c) * NN + l0) = o;
    }
}

extern "C" void kernel_launch(void* const* d_in, const int* in_sizes, int n_in,
                              void* d_out, int out_size, void* d_ws, size_t ws_size,
                              hipStream_t stream) {
    const float* x      = (const float*)d_in[0];
    const float* coords = (const float*)d_in[1];
    const float* sigma  = (const float*)d_in[2];
    const float* weight = (const float*)d_in[3];
    float* out = (float*)d_out;

    dim3 grid(BB * LTILES * CGROUPS);   // 8 * 8 * 16 = 1024 blocks
    sepwconv_kernel<<<grid, THREADS, 0, stream>>>(x, coords, sigma, weight, out);
}

// Round 2
// 22.033 us; speedup vs baseline: 1.0878x; 1.0878x over previous
//
#include <hip/hip_runtime.h>

// SeparableWeightedConv: depthwise 1D conv (K=9, pad=4) with per-(b,l,k)
// distance weights dw = max(1 - dist/sigma, 0), shared across all channels.
// R1: software-pipelined channel loop (prefetch ch i+1 before computing ch i;
// ch 0 loads issued before the sqrt chain) to fix the latency-bound stall.

#define BB 8
#define CC 128
#define NN 8192
#define KK 9

constexpr int CH      = 8;            // channels per block
constexpr int CGROUPS = CC / CH;      // 16
constexpr int LTILE   = 1024;         // l positions per block (256 thr x 4)
constexpr int LTILES  = NN / LTILE;   // 8
constexpr int THREADS = 256;

__device__ __forceinline__ void load12(const float* __restrict__ p, int l0, bool interior,
                                       float4& A, float4& B, float4& C) {
    if (interior) {
        A = *(const float4*)(p + l0 - 4);
        B = *(const float4*)(p + l0);
        C = *(const float4*)(p + l0 + 4);
    } else {
        float t[12];
        #pragma unroll
        for (int j = 0; j < 12; ++j) {
            int q = l0 - 4 + j;
            t[j] = (q >= 0 && q < NN) ? p[q] : 0.0f;   // zero-pad (x path)
        }
        A = make_float4(t[0], t[1], t[2], t[3]);
        B = make_float4(t[4], t[5], t[6], t[7]);
        C = make_float4(t[8], t[9], t[10], t[11]);
    }
}

__global__ __launch_bounds__(THREADS)
void sepwconv_kernel(const float* __restrict__ x,
                     const float* __restrict__ coords,
                     const float* __restrict__ sigma,
                     const float* __restrict__ weight,
                     float* __restrict__ out)
{
    const int bid = blockIdx.x;
    const int cg  = bid % CGROUPS;
    const int lt  = (bid / CGROUPS) % LTILES;
    const int b   = bid / (CGROUPS * LTILES);
    const int t   = threadIdx.x;
    const int l0  = lt * LTILE + t * 4;   // this thread's 4 output positions

    const bool interior = (l0 >= 4) && (l0 + 8 <= NN);
    const float inv_sigma = 1.0f / sigma[0];

    const float* cx = coords + (size_t)(b * 3 + 0) * NN;
    const float* cy = coords + (size_t)(b * 3 + 1) * NN;
    const float* cz = coords + (size_t)(b * 3 + 2) * NN;

    // --- issue coord loads ---
    float cxv[12], cyv[12], czv[12];
    if (interior) {
        float4 a, bq, cq;
        a = *(const float4*)(cx + l0 - 4); bq = *(const float4*)(cx + l0); cq = *(const float4*)(cx + l0 + 4);
        cxv[0]=a.x;cxv[1]=a.y;cxv[2]=a.z;cxv[3]=a.w; cxv[4]=bq.x;cxv[5]=bq.y;cxv[6]=bq.z;cxv[7]=bq.w; cxv[8]=cq.x;cxv[9]=cq.y;cxv[10]=cq.z;cxv[11]=cq.w;
        a = *(const float4*)(cy + l0 - 4); bq = *(const float4*)(cy + l0); cq = *(const float4*)(cy + l0 + 4);
        cyv[0]=a.x;cyv[1]=a.y;cyv[2]=a.z;cyv[3]=a.w; cyv[4]=bq.x;cyv[5]=bq.y;cyv[6]=bq.z;cyv[7]=bq.w; cyv[8]=cq.x;cyv[9]=cq.y;cyv[10]=cq.z;cyv[11]=cq.w;
        a = *(const float4*)(cz + l0 - 4); bq = *(const float4*)(cz + l0); cq = *(const float4*)(cz + l0 + 4);
        czv[0]=a.x;czv[1]=a.y;czv[2]=a.z;czv[3]=a.w; czv[4]=bq.x;czv[5]=bq.y;czv[6]=bq.z;czv[7]=bq.w; czv[8]=cq.x;czv[9]=cq.y;czv[10]=cq.z;czv[11]=cq.w;
    } else {
        #pragma unroll
        for (int j = 0; j < 12; ++j) {
            int p = l0 - 4 + j;
            p = p < 0 ? 0 : (p >= NN ? NN - 1 : p);  // clamp: OOB taps hit x==0 anyway
            cxv[j] = cx[p]; cyv[j] = cy[p]; czv[j] = cz[p];
        }
    }

    // --- issue channel-0 x loads BEFORE the sqrt chain (overlap) ---
    const float* xbase = x + ((size_t)b * CC + cg * CH) * NN;
    float4 XA, XB, XC;
    load12(xbase, l0, interior, XA, XB, XC);

    // --- dw[jl][k]: distance weights, shared across channels ---
    float dw[4][KK];
    #pragma unroll
    for (int jl = 0; jl < 4; ++jl) {
        const float ccx = cxv[jl + 4], ccy = cyv[jl + 4], ccz = czv[jl + 4];
        #pragma unroll
        for (int k = 0; k < KK; ++k) {
            const float dx = cxv[jl + k] - ccx;
            const float dy = cyv[jl + k] - ccy;
            const float dz = czv[jl + k] - ccz;
            const float sq = fmaf(dx, dx, fmaf(dy, dy, dz * dz));
            const float dist = sqrtf(sq);              // sq==0 -> 0, matches ref
            dw[jl][k] = fmaxf(1.0f - dist * inv_sigma, 0.0f);
        }
    }

    // --- software-pipelined channel loop ---
    #pragma unroll 1
    for (int i = 0; i < CH; ++i) {
        // prefetch next channel's x while we compute this one
        float4 NA, NB, NC;
        if (i + 1 < CH) load12(xbase + (size_t)(i + 1) * NN, l0, interior, NA, NB, NC);

        const int c = cg * CH + i;
        const float* wr = weight + c * KK;   // wave-uniform -> s_load
        float w[KK];
        #pragma unroll
        for (int k = 0; k < KK; ++k) w[k] = wr[k];

        float xv[12] = {XA.x, XA.y, XA.z, XA.w, XB.x, XB.y, XB.z, XB.w, XC.x, XC.y, XC.z, XC.w};

        float acc[4] = {0.f, 0.f, 0.f, 0.f};
        #pragma unroll
        for (int jl = 0; jl < 4; ++jl) {
            #pragma unroll
            for (int k = 0; k < KK; ++k) {
                acc[jl] = fmaf(xv[jl + k] * dw[jl][k], w[k], acc[jl]);
            }
        }

        float4 o; o.x = acc[0]; o.y = acc[1]; o.z = acc[2]; o.w = acc[3];
        *(float4*)(out + ((size_t)b * CC + c) * NN + l0) = o;

        if (i + 1 < CH) { XA = NA; XB = NB; XC = NC; }
    }
}

extern "C" void kernel_launch(void* const* d_in, const int* in_sizes, int n_in,
                              void* d_out, int out_size, void* d_ws, size_t ws_size,
                              hipStream_t stream) {
    const float* x      = (const float*)d_in[0];
    const float* coords = (const float*)d_in[1];
    const float* sigma  = (const float*)d_in[2];
    const float* weight = (const float*)d_in[3];
    float* out = (float*)d_out;

    dim3 grid(BB * LTILES * CGROUPS);   // 8 * 8 * 16 = 1024 blocks
    sepwconv_kernel<<<grid, THREADS, 0, stream>>>(x, coords, sigma, weight, out);
}